// Round 13
// baseline (615.645 us; speedup 1.0000x reference)
//
#include <hip/hip_runtime.h>

#define NEGV (-1e9f)

static const int B_ = 16;
static const int T_ = 2048;
static const int S_ = 512;
static const int C_ = 192;

typedef unsigned short ushort_t;
using f32x4 = __attribute__((ext_vector_type(4))) float;
using s16x8 = __attribute__((ext_vector_type(8))) short;

// split f32 into bf16 hi + bf16 lo (x ~= hi + lo, residual ~2^-18 |x|)
__device__ __forceinline__ void split2(float x, ushort_t& h, ushort_t& l) {
    __bf16 hb = (__bf16)x;
    h = __builtin_bit_cast(ushort_t, hb);
    float r = x - (float)hb;
    __bf16 lb = (__bf16)r;
    l = __builtin_bit_cast(ushort_t, lb);
}

// ---------------- prep: Bcat = [m*s2r | s2r] split to bf16 hi/lo; nc14 ----------------
__global__ __launch_bounds__(256)
void prep_kernel(const float* __restrict__ m_p, const float* __restrict__ logs_p,
                 ushort_t* __restrict__ Bh, ushort_t* __restrict__ Bl,
                 float* __restrict__ nc14) {
    int wid = (blockIdx.x * blockDim.x + threadIdx.x) >> 6;   // (b*S+s)
    int lane = threadIdx.x & 63;
    if (wid >= B_ * S_) return;
    const float HALF_LOG_2PI = 0.9189385332046727f;
    const float* mrow = m_p    + (size_t)wid * C_;
    const float* lrow = logs_p + (size_t)wid * C_;
    ushort_t* bh = Bh + (size_t)wid * 384;
    ushort_t* bl = Bl + (size_t)wid * 384;
    float tot = 0.f;
#pragma unroll
    for (int q = 0; q < 3; ++q) {
        int c = lane + q * 64;
        float m  = mrow[c];
        float lp = lrow[c];
        float s2r = __expf(-2.f * lp);
        float a = m * s2r;
        ushort_t h, l;
        split2(a, h, l);   bh[c] = h;        bl[c] = l;
        split2(s2r, h, l); bh[192 + c] = h;  bl[192 + c] = l;
        tot += (-HALF_LOG_2PI - lp) + (-0.5f * m * m * s2r);
    }
#pragma unroll
    for (int off = 32; off > 0; off >>= 1) tot += __shfl_xor(tot, off);
    if (lane == 0) nc14[wid] = tot;
}

// ---------------- GEMM (split-bf16 MFMA, 2 products): ll = masked(nc14 + A(z)*Bcat) ----------------
// Early-out: tiles fully above mellen (t0>=ml) or right of textlen (s0>=tl)
// are pure NEGV — skip staging and MFMA entirely.
// 2-product split (Ah*Bh + Ah*Bl): residual ~sqrt(K)*2^-9 ~ 0.04 in ll —
// 6x below the f16-ll error that already passed (R7/R8).
#define LDP 40   // LDS row stride in bf16 elems (32 + 8 pad)
__global__ __launch_bounds__(256)
void gemm_kernel(const float* __restrict__ z_p,
                 const ushort_t* __restrict__ Bh, const ushort_t* __restrict__ Bl,
                 const float* __restrict__ nc14,
                 const int* __restrict__ textlen, const int* __restrict__ mellen,
                 float* __restrict__ ll) {
    __shared__ ushort_t sAh[128 * LDP];
    __shared__ ushort_t sAl[128 * LDP];
    __shared__ ushort_t sBh[128 * LDP];
    __shared__ ushort_t sBl[128 * LDP];

    const int b  = blockIdx.z;
    const int t0 = blockIdx.y * 128;
    const int s0 = blockIdx.x * 128;
    const int tid = threadIdx.x;
    const int lane = tid & 63;
    const int wave = tid >> 6;
    const int wr = wave >> 1, wc = wave & 1;
    const int srow = tid >> 1;
    const int cb = (tid & 1) * 16;

    const int ml = mellen[b], tl = textlen[b];
    const int r15 = lane & 15;
    const int klane = (lane >> 4) * 8;

    // ---- fully-masked tile: write NEGV and exit ----
    if (t0 >= ml || s0 >= tl) {
        int scol[4];
#pragma unroll
        for (int n = 0; n < 4; ++n) scol[n] = s0 + wc * 64 + n * 16 + r15;
#pragma unroll
        for (int m = 0; m < 4; ++m) {
            const int tb = t0 + wr * 64 + m * 16 + (lane >> 4) * 4;
#pragma unroll
            for (int r = 0; r < 4; ++r) {
                float* orow = ll + ((size_t)b * T_ + tb + r) * S_;
#pragma unroll
                for (int n = 0; n < 4; ++n) orow[scol[n]] = NEGV;
            }
        }
        return;
    }

    f32x4 acc[4][4];
#pragma unroll
    for (int m = 0; m < 4; ++m)
#pragma unroll
        for (int n = 0; n < 4; ++n) acc[m][n] = (f32x4){0.f, 0.f, 0.f, 0.f};

    for (int kk = 0; kk < 12; ++kk) {
        // ---- stage A from z_p (convert + split hi/lo, only hi used for MFMA A) ----
        {
            const int ck = (kk < 6 ? kk * 32 : (kk - 6) * 32) + cb;
            const float* src = z_p + ((size_t)b * T_ + t0 + srow) * C_ + ck;
            float e[16];
            *(float4*)(e + 0)  = *(const float4*)(src + 0);
            *(float4*)(e + 4)  = *(const float4*)(src + 4);
            *(float4*)(e + 8)  = *(const float4*)(src + 8);
            *(float4*)(e + 12) = *(const float4*)(src + 12);
            if (kk >= 6) {
#pragma unroll
                for (int i = 0; i < 16; ++i) e[i] = -0.5f * e[i] * e[i];
            }
            ushort_t h[16], l[16];
#pragma unroll
            for (int i = 0; i < 16; ++i) split2(e[i], h[i], l[i]);
            ushort_t* dh = &sAh[srow * LDP + cb];
            ushort_t* dl = &sAl[srow * LDP + cb];
            *(uint4*)dh = make_uint4(h[0] | (h[1] << 16), h[2] | (h[3] << 16),
                                     h[4] | (h[5] << 16), h[6] | (h[7] << 16));
            *(uint4*)(dh + 8) = make_uint4(h[8] | (h[9] << 16), h[10] | (h[11] << 16),
                                           h[12] | (h[13] << 16), h[14] | (h[15] << 16));
            *(uint4*)dl = make_uint4(l[0] | (l[1] << 16), l[2] | (l[3] << 16),
                                     l[4] | (l[5] << 16), l[6] | (l[7] << 16));
            *(uint4*)(dl + 8) = make_uint4(l[8] | (l[9] << 16), l[10] | (l[11] << 16),
                                           l[12] | (l[13] << 16), l[14] | (l[15] << 16));
        }
        // ---- stage B from Bcat (already bf16 hi/lo) ----
        {
            const size_t off = ((size_t)b * S_ + s0 + srow) * 384 + kk * 32 + cb;
            const uint4 u0 = *(const uint4*)(Bh + off);
            const uint4 u1 = *(const uint4*)(Bh + off + 8);
            const uint4 v0 = *(const uint4*)(Bl + off);
            const uint4 v1 = *(const uint4*)(Bl + off + 8);
            ushort_t* dh = &sBh[srow * LDP + cb];
            ushort_t* dl = &sBl[srow * LDP + cb];
            *(uint4*)dh = u0; *(uint4*)(dh + 8) = u1;
            *(uint4*)dl = v0; *(uint4*)(dl + 8) = v1;
        }
        __syncthreads();

        s16x8 ah[4], al[4], bhf[4], blf[4];
#pragma unroll
        for (int m = 0; m < 4; ++m) {
            const int row = wr * 64 + m * 16 + r15;
            ah[m] = *(const s16x8*)&sAh[row * LDP + klane];
            al[m] = *(const s16x8*)&sAl[row * LDP + klane];
        }
#pragma unroll
        for (int n = 0; n < 4; ++n) {
            const int row = wc * 64 + n * 16 + r15;
            bhf[n] = *(const s16x8*)&sBh[row * LDP + klane];
            blf[n] = *(const s16x8*)&sBl[row * LDP + klane];
        }
#pragma unroll
        for (int m = 0; m < 4; ++m)
#pragma unroll
            for (int n = 0; n < 4; ++n) {
                acc[m][n] = __builtin_amdgcn_mfma_f32_16x16x32_bf16(ah[m], bhf[n], acc[m][n], 0, 0, 0);
                acc[m][n] = __builtin_amdgcn_mfma_f32_16x16x32_bf16(ah[m], blf[n], acc[m][n], 0, 0, 0);
                acc[m][n] = __builtin_amdgcn_mfma_f32_16x16x32_bf16(al[m], bhf[n], acc[m][n], 0, 0, 0);
            }
        __syncthreads();
    }

    // ---- epilogue: + nc14, mask, store f32 ----
    int scol[4]; float ncv[4];
#pragma unroll
    for (int n = 0; n < 4; ++n) {
        scol[n] = s0 + wc * 64 + n * 16 + r15;
        ncv[n] = nc14[b * S_ + scol[n]];
    }
#pragma unroll
    for (int m = 0; m < 4; ++m) {
        const int tb = t0 + wr * 64 + m * 16 + (lane >> 4) * 4;
#pragma unroll
        for (int r = 0; r < 4; ++r) {
            const int t = tb + r;
            const bool tm = (t < ml);
            float* orow = ll + ((size_t)b * T_ + t) * S_;
#pragma unroll
            for (int n = 0; n < 4; ++n)
                orow[scol[n]] = (tm && scol[n] < tl) ? (acc[m][n][r] + ncv[n]) : NEGV;
        }
    }
}

// ---------------- MAS forward: R11-exact locked schedule + ml-trim ----------------
// Direction bits for t >= mellen[b] are never read by the backward pass
// (backtrack starts at ml-1), so the unmasked loop runs only to ceil(ml/8).
__global__ __launch_bounds__(64)
void mas_forward(const float* __restrict__ ll, const int* __restrict__ mellen,
                 unsigned char* __restrict__ dir) {
    const int b = blockIdx.x;
    const int lane = threadIdx.x;
    const float* llb = ll + (size_t)b * T_ * S_ + lane * 8;
    unsigned char* db = dir + ((size_t)b * T_) * 64 + lane;
    const int sbase = lane * 8;
    const int mlg = (mellen[b] + 7) >> 3;   // groups to compute (ml >= 1024 > 512)

    float4 pre[8][2];
#pragma unroll
    for (int r = 0; r < 8; ++r) {
        pre[r][0] = *(const float4*)(llb + (size_t)r * S_);
        pre[r][1] = *(const float4*)(llb + (size_t)r * S_ + 4);
    }

    float p[8];
#pragma unroll
    for (int j = 0; j < 8; ++j) p[j] = 0.f;
    float carry = (lane == 0) ? NEGV : 0.f;

    auto step = [&](int t, int ph, bool masked) {
        float cur[8];
        cur[0] = pre[ph][0].x; cur[1] = pre[ph][0].y;
        cur[2] = pre[ph][0].z; cur[3] = pre[ph][0].w;
        cur[4] = pre[ph][1].x; cur[5] = pre[ph][1].y;
        cur[6] = pre[ph][1].z; cur[7] = pre[ph][1].w;
        const int tn = t + 8;
        if (tn < T_) {
            pre[ph][0] = *(const float4*)(llb + (size_t)tn * S_);
            pre[ph][1] = *(const float4*)(llb + (size_t)tn * S_ + 4);
        }
        float v7 = fmaxf(p[7], p[6]) + cur[7];
        float nc7 = masked ? ((sbase + 7 <= t) ? v7 : NEGV) : v7;
        float newcarry = __shfl_up(nc7, 1);

        unsigned bits = (p[0] >= carry) ? 1u : 0u;
#pragma unroll
        for (int j = 1; j < 8; ++j)
            bits |= (p[j] >= p[j - 1] ? 1u : 0u) << j;

        float nv[8];
        nv[0] = fmaxf(p[0], carry) + cur[0];
#pragma unroll
        for (int j = 1; j < 7; ++j) nv[j] = fmaxf(p[j], p[j - 1]) + cur[j];
        nv[7] = v7;
        if (masked) {
#pragma unroll
            for (int j = 0; j < 8; ++j)
                p[j] = (sbase + j <= t) ? nv[j] : NEGV;
        } else {
#pragma unroll
            for (int j = 0; j < 8; ++j) p[j] = nv[j];
        }
        carry = (lane == 0) ? NEGV : newcarry;
        db[(size_t)t * 64] = (unsigned char)bits;
    };

    // masked phase: t in [0,512)  (ml >= 1024, so always full)
    for (int to = 0; to < S_ / 8; ++to) {
#pragma unroll
        for (int ph = 0; ph < 8; ++ph) step(to * 8 + ph, ph, true);
    }
    // unmasked phase: t in [512, ceil(ml/8)*8)
    for (int to = S_ / 8; to < mlg; ++to) {
#pragma unroll
        for (int ph = 0; ph < 8; ++ph) step(to * 8 + ph, ph, false);
    }
}

// ---------------- MAS backward: 8-step speculative groups, emits idx[b,t] ----------------
__global__ __launch_bounds__(64)
void mas_backward(const unsigned char* __restrict__ dir,
                  const int* __restrict__ textlen, const int* __restrict__ mellen,
                  int* __restrict__ idx_arr) {
    const int b = blockIdx.x;
    const int lane = threadIdx.x;
    const int tl = textlen[b], ml = mellen[b];
    for (int t = ml + lane; t < T_; t += 64) idx_arr[b * T_ + t] = -1;
    const unsigned char* db = dir + (size_t)b * T_ * 64;
    int idx = tl - 1;
    int t_hi = ml - 1;
    while (t_hi >= 0) {
        const int lo = idx - 7;
        const int blo = (lo > 0 ? lo : 0) >> 3;
        const int bhi = idx >> 3;
        const int t = t_hi - lane;
        unsigned v = 0;
        if (lane < 8 && t >= 0) {
            unsigned b0 = db[(size_t)t * 64 + blo];
            unsigned b1 = db[(size_t)t * 64 + bhi];
            v = b0 | (b1 << 8);
        }
        unsigned vk[8];
#pragma unroll
        for (int k = 0; k < 8; ++k) vk[k] = __shfl((int)v, k);
        int emit = -1;
#pragma unroll
        for (int k = 0; k < 8; ++k) {
            const int tt = t_hi - k;
            if (tt < 0) break;
            if (lane == k) emit = idx;
            const int sb = idx >> 3;
            const unsigned byte = (sb == bhi) ? (vk[k] >> 8) : (vk[k] & 0xffu);
            const int stay = (byte >> (idx & 7)) & 1;
            idx -= (1 - stay);
            if (idx < 0) idx = 0;
        }
        const int tt = t_hi - lane;
        if (lane < 8 && tt >= 0) idx_arr[b * T_ + tt] = emit;
        t_hi -= 8;
    }
}

// ---------------- fused attn write + per-frame kl ----------------
__global__ __launch_bounds__(256)
void attn_kl(const float* __restrict__ m_p, const float* __restrict__ logs_p,
             const float* __restrict__ z_p, const float* __restrict__ logs_q,
             const int* __restrict__ idx_arr, const int* __restrict__ mellen,
             float* __restrict__ attn, float* __restrict__ frame_kl) {
    const int wid = (blockIdx.x * blockDim.x + threadIdx.x) >> 6;  // b*T + t
    const int lane = threadIdx.x & 63;
    if (wid >= B_ * T_) return;
    const int b = wid >> 11;       // T_ = 2048
    const int t = wid & (T_ - 1);
    const int ml = mellen[b];
    const int idx = idx_arr[wid];  // -1 for t >= ml

    float* row = attn + (size_t)wid * S_;
#pragma unroll
    for (int j = 0; j < 8; ++j) {
        const int s = j * 64 + lane;
        row[s] = (s == idx) ? 1.0f : 0.0f;
    }

    float total = 0.f;
    if (t < ml) {
        const float* mr = m_p    + ((size_t)b * S_ + idx) * C_;
        const float* lr = logs_p + ((size_t)b * S_ + idx) * C_;
        const float* zr = z_p    + (size_t)wid * C_;
        const float* qr = logs_q + (size_t)wid * C_;
#pragma unroll
        for (int q = 0; q < 3; ++q) {
            const int c = lane + q * 64;
            const float le = lr[c];
            const float d = zr[c] - mr[c];
            total += le - qr[c] - 0.5f + 0.5f * d * d * __expf(-2.f * le);
        }
    }
#pragma unroll
    for (int off = 32; off > 0; off >>= 1) total += __shfl_xor(total, off);
    if (lane == 0) frame_kl[wid] = total;
}

// ---------------- deterministic final reduce ----------------
__global__ __launch_bounds__(256)
void kl_reduce(const float* __restrict__ frame_kl, const int* __restrict__ mellen,
               float* __restrict__ out) {
    __shared__ float sm[256];
    const int tid = threadIdx.x;
    float s = 0.f;
    for (int k = tid; k < B_ * T_; k += 256) s += frame_kl[k];
    sm[tid] = s;
    __syncthreads();
    for (int off = 128; off > 0; off >>= 1) {
        if (tid < off) sm[tid] += sm[tid + off];
        __syncthreads();
    }
    if (tid == 0) {
        int sum_ml = 0;
        for (int bq = 0; bq < B_; ++bq) sum_ml += mellen[bq];
        out[0] = sm[0] / (float)sum_ml;
    }
}

extern "C" void kernel_launch(void* const* d_in, const int* in_sizes, int n_in,
                              void* d_out, int out_size, void* d_ws, size_t ws_size,
                              hipStream_t stream) {
    const float* m_p    = (const float*)d_in[0];
    const float* logs_p = (const float*)d_in[1];
    const float* z_p    = (const float*)d_in[2];
    const float* logs_q = (const float*)d_in[3];
    const int*   textlen = (const int*)d_in[4];
    const int*   mellen  = (const int*)d_in[5];

    float* out = (float*)d_out;
    float* attn = out + 1;                 // [B,T,S] region; also used as ll scratch
    float* ll = attn;

    char* ws = (char*)d_ws;
    const size_t OFF_BH   = 0;
    const size_t OFF_BL   = OFF_BH + (size_t)B_ * S_ * 384 * 2;  //  6291456
    const size_t OFF_NC   = OFF_BL + (size_t)B_ * S_ * 384 * 2;  // 12582912
    const size_t OFF_DIR  = OFF_NC + (size_t)B_ * S_ * 4;        // 12615680
    const size_t OFF_IDX  = OFF_DIR + (size_t)B_ * T_ * 64;      // 14712832
    const size_t OFF_FKL  = OFF_IDX + (size_t)B_ * T_ * 4;       // 14843904
    ushort_t* Bh = (ushort_t*)(ws + OFF_BH);
    ushort_t* Bl = (ushort_t*)(ws + OFF_BL);
    float* nc14 = (float*)(ws + OFF_NC);
    unsigned char* dir = (unsigned char*)(ws + OFF_DIR);
    int* idx_arr = (int*)(ws + OFF_IDX);
    float* frame_kl = (float*)(ws + OFF_FKL);

    // 1. prep (split B-side to bf16 hi/lo + nc14)
    prep_kernel<<<(B_ * S_) / 4, 256, 0, stream>>>(m_p, logs_p, Bh, Bl, nc14);
    // 2. score GEMM (split-bf16 MFMA, masked-tile early-out) -> f32 ll
    gemm_kernel<<<dim3(S_ / 128, T_ / 128, B_), 256, 0, stream>>>(
        z_p, Bh, Bl, nc14, textlen, mellen, ll);
    // 3. MAS forward (R11-exact locked schedule + ml-trim)
    mas_forward<<<B_, 64, 0, stream>>>(ll, mellen, dir);
    // 4. MAS backward -> idx per frame
    mas_backward<<<B_, 64, 0, stream>>>(dir, textlen, mellen, idx_arr);
    // 5. fused attn write + per-frame kl
    attn_kl<<<(B_ * T_) / 4, 256, 0, stream>>>(m_p, logs_p, z_p, logs_q,
                                               idx_arr, mellen, attn, frame_kl);
    // 6. final reduce
    kl_reduce<<<1, 256, 0, stream>>>(frame_kl, mellen, out);
}

// Round 14
// 486.653 us; speedup vs baseline: 1.2651x; 1.2651x over previous
//
#include <hip/hip_runtime.h>

#define NEGV (-1e9f)

static const int B_ = 16;
static const int T_ = 2048;
static const int S_ = 512;
static const int C_ = 192;

typedef unsigned short ushort_t;
using f32x4 = __attribute__((ext_vector_type(4))) float;
using s16x8 = __attribute__((ext_vector_type(8))) short;

// split f32 into bf16 hi + bf16 lo (x ~= hi + lo, residual ~2^-18 |x|)
__device__ __forceinline__ void split2(float x, ushort_t& h, ushort_t& l) {
    __bf16 hb = (__bf16)x;
    h = __builtin_bit_cast(ushort_t, hb);
    float r = x - (float)hb;
    __bf16 lb = (__bf16)r;
    l = __builtin_bit_cast(ushort_t, lb);
}

__device__ __forceinline__ ushort_t to_bf16(float x) {
    return __builtin_bit_cast(ushort_t, (__bf16)x);
}

// ---------------- prep: Bcat = [m*s2r | s2r] split to bf16 hi/lo; nc14 ----------------
__global__ __launch_bounds__(256)
void prep_kernel(const float* __restrict__ m_p, const float* __restrict__ logs_p,
                 ushort_t* __restrict__ Bh, ushort_t* __restrict__ Bl,
                 float* __restrict__ nc14) {
    int wid = (blockIdx.x * blockDim.x + threadIdx.x) >> 6;   // (b*S+s)
    int lane = threadIdx.x & 63;
    if (wid >= B_ * S_) return;
    const float HALF_LOG_2PI = 0.9189385332046727f;
    const float* mrow = m_p    + (size_t)wid * C_;
    const float* lrow = logs_p + (size_t)wid * C_;
    ushort_t* bh = Bh + (size_t)wid * 384;
    ushort_t* bl = Bl + (size_t)wid * 384;
    float tot = 0.f;
#pragma unroll
    for (int q = 0; q < 3; ++q) {
        int c = lane + q * 64;
        float m  = mrow[c];
        float lp = lrow[c];
        float s2r = __expf(-2.f * lp);
        float a = m * s2r;
        ushort_t h, l;
        split2(a, h, l);   bh[c] = h;        bl[c] = l;
        split2(s2r, h, l); bh[192 + c] = h;  bl[192 + c] = l;
        tot += (-HALF_LOG_2PI - lp) + (-0.5f * m * m * s2r);
    }
#pragma unroll
    for (int off = 32; off > 0; off >>= 1) tot += __shfl_xor(tot, off);
    if (lane == 0) nc14[wid] = tot;
}

// ---------------- GEMM (split-bf16, 2 products): ll = masked(nc14 + A(z)*Bcat) ----------------
// A is bf16(hi) only; B keeps hi+lo. Dropped al*bh product: residual
// ~sqrt(384)*2^-9*rms(a)*rms(b) ~ 0.05 in ll — 5x below the f16 error that
// passed in R7/R8. Saves sAl staging (LDS 40->30KB) and 1/3 of MFMAs.
#define LDP 40   // LDS row stride in bf16 elems (32 + 8 pad)
__global__ __launch_bounds__(256)
void gemm_kernel(const float* __restrict__ z_p,
                 const ushort_t* __restrict__ Bh, const ushort_t* __restrict__ Bl,
                 const float* __restrict__ nc14,
                 const int* __restrict__ textlen, const int* __restrict__ mellen,
                 float* __restrict__ ll) {
    __shared__ ushort_t sAh[128 * LDP];
    __shared__ ushort_t sBh[128 * LDP];
    __shared__ ushort_t sBl[128 * LDP];

    const int b  = blockIdx.z;
    const int t0 = blockIdx.y * 128;
    const int s0 = blockIdx.x * 128;
    const int tid = threadIdx.x;
    const int lane = tid & 63;
    const int wave = tid >> 6;
    const int wr = wave >> 1, wc = wave & 1;
    const int srow = tid >> 1;
    const int cb = (tid & 1) * 16;

    const int ml = mellen[b], tl = textlen[b];
    const int r15 = lane & 15;
    const int klane = (lane >> 4) * 8;

    // ---- fully-masked tile: write NEGV and exit ----
    if (t0 >= ml || s0 >= tl) {
        int scol[4];
#pragma unroll
        for (int n = 0; n < 4; ++n) scol[n] = s0 + wc * 64 + n * 16 + r15;
#pragma unroll
        for (int m = 0; m < 4; ++m) {
            const int tb = t0 + wr * 64 + m * 16 + (lane >> 4) * 4;
#pragma unroll
            for (int r = 0; r < 4; ++r) {
                float* orow = ll + ((size_t)b * T_ + tb + r) * S_;
#pragma unroll
                for (int n = 0; n < 4; ++n) orow[scol[n]] = NEGV;
            }
        }
        return;
    }

    f32x4 acc[4][4];
#pragma unroll
    for (int m = 0; m < 4; ++m)
#pragma unroll
        for (int n = 0; n < 4; ++n) acc[m][n] = (f32x4){0.f, 0.f, 0.f, 0.f};

    for (int kk = 0; kk < 12; ++kk) {
        // ---- stage A from z_p (convert to bf16 hi only) ----
        {
            const int ck = (kk < 6 ? kk * 32 : (kk - 6) * 32) + cb;
            const float* src = z_p + ((size_t)b * T_ + t0 + srow) * C_ + ck;
            float e[16];
            *(float4*)(e + 0)  = *(const float4*)(src + 0);
            *(float4*)(e + 4)  = *(const float4*)(src + 4);
            *(float4*)(e + 8)  = *(const float4*)(src + 8);
            *(float4*)(e + 12) = *(const float4*)(src + 12);
            if (kk >= 6) {
#pragma unroll
                for (int i = 0; i < 16; ++i) e[i] = -0.5f * e[i] * e[i];
            }
            ushort_t h[16];
#pragma unroll
            for (int i = 0; i < 16; ++i) h[i] = to_bf16(e[i]);
            ushort_t* dh = &sAh[srow * LDP + cb];
            *(uint4*)dh = make_uint4(h[0] | (h[1] << 16), h[2] | (h[3] << 16),
                                     h[4] | (h[5] << 16), h[6] | (h[7] << 16));
            *(uint4*)(dh + 8) = make_uint4(h[8] | (h[9] << 16), h[10] | (h[11] << 16),
                                           h[12] | (h[13] << 16), h[14] | (h[15] << 16));
        }
        // ---- stage B from Bcat (already bf16 hi/lo) ----
        {
            const size_t off = ((size_t)b * S_ + s0 + srow) * 384 + kk * 32 + cb;
            const uint4 u0 = *(const uint4*)(Bh + off);
            const uint4 u1 = *(const uint4*)(Bh + off + 8);
            const uint4 v0 = *(const uint4*)(Bl + off);
            const uint4 v1 = *(const uint4*)(Bl + off + 8);
            ushort_t* dh = &sBh[srow * LDP + cb];
            ushort_t* dl = &sBl[srow * LDP + cb];
            *(uint4*)dh = u0; *(uint4*)(dh + 8) = u1;
            *(uint4*)dl = v0; *(uint4*)(dl + 8) = v1;
        }
        __syncthreads();

        s16x8 ah[4], bhf[4], blf[4];
#pragma unroll
        for (int m = 0; m < 4; ++m) {
            const int row = wr * 64 + m * 16 + r15;
            ah[m] = *(const s16x8*)&sAh[row * LDP + klane];
        }
#pragma unroll
        for (int n = 0; n < 4; ++n) {
            const int row = wc * 64 + n * 16 + r15;
            bhf[n] = *(const s16x8*)&sBh[row * LDP + klane];
            blf[n] = *(const s16x8*)&sBl[row * LDP + klane];
        }
#pragma unroll
        for (int m = 0; m < 4; ++m)
#pragma unroll
            for (int n = 0; n < 4; ++n) {
                acc[m][n] = __builtin_amdgcn_mfma_f32_16x16x32_bf16(ah[m], bhf[n], acc[m][n], 0, 0, 0);
                acc[m][n] = __builtin_amdgcn_mfma_f32_16x16x32_bf16(ah[m], blf[n], acc[m][n], 0, 0, 0);
            }
        __syncthreads();
    }

    // ---- epilogue: + nc14, mask, store f32 ----
    int scol[4]; float ncv[4];
#pragma unroll
    for (int n = 0; n < 4; ++n) {
        scol[n] = s0 + wc * 64 + n * 16 + r15;
        ncv[n] = nc14[b * S_ + scol[n]];
    }
#pragma unroll
    for (int m = 0; m < 4; ++m) {
        const int tb = t0 + wr * 64 + m * 16 + (lane >> 4) * 4;
#pragma unroll
        for (int r = 0; r < 4; ++r) {
            const int t = tb + r;
            const bool tm = (t < ml);
            float* orow = ll + ((size_t)b * T_ + t) * S_;
#pragma unroll
            for (int n = 0; n < 4; ++n)
                orow[scol[n]] = (tm && scol[n] < tl) ? (acc[m][n][r] + ncv[n]) : NEGV;
        }
    }
}

// ---------------- MAS forward: R11-EXACT locked schedule (do not touch) ----------------
__global__ __launch_bounds__(64)
void mas_forward(const float* __restrict__ ll, unsigned char* __restrict__ dir) {
    const int b = blockIdx.x;
    const int lane = threadIdx.x;
    const float* llb = ll + (size_t)b * T_ * S_ + lane * 8;
    unsigned char* db = dir + ((size_t)b * T_) * 64 + lane;
    const int sbase = lane * 8;

    float4 pre[8][2];
#pragma unroll
    for (int r = 0; r < 8; ++r) {
        pre[r][0] = *(const float4*)(llb + (size_t)r * S_);
        pre[r][1] = *(const float4*)(llb + (size_t)r * S_ + 4);
    }

    float p[8];
#pragma unroll
    for (int j = 0; j < 8; ++j) p[j] = 0.f;
    float carry = (lane == 0) ? NEGV : 0.f;

    auto step = [&](int t, int ph, bool masked) {
        float cur[8];
        cur[0] = pre[ph][0].x; cur[1] = pre[ph][0].y;
        cur[2] = pre[ph][0].z; cur[3] = pre[ph][0].w;
        cur[4] = pre[ph][1].x; cur[5] = pre[ph][1].y;
        cur[6] = pre[ph][1].z; cur[7] = pre[ph][1].w;
        const int tn = t + 8;
        if (tn < T_) {
            pre[ph][0] = *(const float4*)(llb + (size_t)tn * S_);
            pre[ph][1] = *(const float4*)(llb + (size_t)tn * S_ + 4);
        }
        float v7 = fmaxf(p[7], p[6]) + cur[7];
        float nc7 = masked ? ((sbase + 7 <= t) ? v7 : NEGV) : v7;
        float newcarry = __shfl_up(nc7, 1);

        unsigned bits = (p[0] >= carry) ? 1u : 0u;
#pragma unroll
        for (int j = 1; j < 8; ++j)
            bits |= (p[j] >= p[j - 1] ? 1u : 0u) << j;

        float nv[8];
        nv[0] = fmaxf(p[0], carry) + cur[0];
#pragma unroll
        for (int j = 1; j < 7; ++j) nv[j] = fmaxf(p[j], p[j - 1]) + cur[j];
        nv[7] = v7;
        if (masked) {
#pragma unroll
            for (int j = 0; j < 8; ++j)
                p[j] = (sbase + j <= t) ? nv[j] : NEGV;
        } else {
#pragma unroll
            for (int j = 0; j < 8; ++j) p[j] = nv[j];
        }
        carry = (lane == 0) ? NEGV : newcarry;
        db[(size_t)t * 64] = (unsigned char)bits;
    };

    for (int to = 0; to < S_ / 8; ++to) {
#pragma unroll
        for (int ph = 0; ph < 8; ++ph) step(to * 8 + ph, ph, true);
    }
    for (int to = S_ / 8; to < T_ / 8; ++to) {
#pragma unroll
        for (int ph = 0; ph < 8; ++ph) step(to * 8 + ph, ph, false);
    }
}

// ---------------- MAS backward: 8-step speculative groups, emits idx[b,t] ----------------
__global__ __launch_bounds__(64)
void mas_backward(const unsigned char* __restrict__ dir,
                  const int* __restrict__ textlen, const int* __restrict__ mellen,
                  int* __restrict__ idx_arr) {
    const int b = blockIdx.x;
    const int lane = threadIdx.x;
    const int tl = textlen[b], ml = mellen[b];
    for (int t = ml + lane; t < T_; t += 64) idx_arr[b * T_ + t] = -1;
    const unsigned char* db = dir + (size_t)b * T_ * 64;
    int idx = tl - 1;
    int t_hi = ml - 1;
    while (t_hi >= 0) {
        const int lo = idx - 7;
        const int blo = (lo > 0 ? lo : 0) >> 3;
        const int bhi = idx >> 3;
        const int t = t_hi - lane;
        unsigned v = 0;
        if (lane < 8 && t >= 0) {
            unsigned b0 = db[(size_t)t * 64 + blo];
            unsigned b1 = db[(size_t)t * 64 + bhi];
            v = b0 | (b1 << 8);
        }
        unsigned vk[8];
#pragma unroll
        for (int k = 0; k < 8; ++k) vk[k] = __shfl((int)v, k);
        int emit = -1;
#pragma unroll
        for (int k = 0; k < 8; ++k) {
            const int tt = t_hi - k;
            if (tt < 0) break;
            if (lane == k) emit = idx;
            const int sb = idx >> 3;
            const unsigned byte = (sb == bhi) ? (vk[k] >> 8) : (vk[k] & 0xffu);
            const int stay = (byte >> (idx & 7)) & 1;
            idx -= (1 - stay);
            if (idx < 0) idx = 0;
        }
        const int tt = t_hi - lane;
        if (lane < 8 && tt >= 0) idx_arr[b * T_ + tt] = emit;
        t_hi -= 8;
    }
}

// ---------------- fused attn write + per-frame kl ----------------
__global__ __launch_bounds__(256)
void attn_kl(const float* __restrict__ m_p, const float* __restrict__ logs_p,
             const float* __restrict__ z_p, const float* __restrict__ logs_q,
             const int* __restrict__ idx_arr, const int* __restrict__ mellen,
             float* __restrict__ attn, float* __restrict__ frame_kl) {
    const int wid = (blockIdx.x * blockDim.x + threadIdx.x) >> 6;  // b*T + t
    const int lane = threadIdx.x & 63;
    if (wid >= B_ * T_) return;
    const int b = wid >> 11;       // T_ = 2048
    const int t = wid & (T_ - 1);
    const int ml = mellen[b];
    const int idx = idx_arr[wid];  // -1 for t >= ml

    float* row = attn + (size_t)wid * S_;
#pragma unroll
    for (int j = 0; j < 8; ++j) {
        const int s = j * 64 + lane;
        row[s] = (s == idx) ? 1.0f : 0.0f;
    }

    float total = 0.f;
    if (t < ml) {
        const float* mr = m_p    + ((size_t)b * S_ + idx) * C_;
        const float* lr = logs_p + ((size_t)b * S_ + idx) * C_;
        const float* zr = z_p    + (size_t)wid * C_;
        const float* qr = logs_q + (size_t)wid * C_;
#pragma unroll
        for (int q = 0; q < 3; ++q) {
            const int c = lane + q * 64;
            const float le = lr[c];
            const float d = zr[c] - mr[c];
            total += le - qr[c] - 0.5f + 0.5f * d * d * __expf(-2.f * le);
        }
    }
#pragma unroll
    for (int off = 32; off > 0; off >>= 1) total += __shfl_xor(total, off);
    if (lane == 0) frame_kl[wid] = total;
}

// ---------------- deterministic final reduce ----------------
__global__ __launch_bounds__(256)
void kl_reduce(const float* __restrict__ frame_kl, const int* __restrict__ mellen,
               float* __restrict__ out) {
    __shared__ float sm[256];
    const int tid = threadIdx.x;
    float s = 0.f;
    for (int k = tid; k < B_ * T_; k += 256) s += frame_kl[k];
    sm[tid] = s;
    __syncthreads();
    for (int off = 128; off > 0; off >>= 1) {
        if (tid < off) sm[tid] += sm[tid + off];
        __syncthreads();
    }
    if (tid == 0) {
        int sum_ml = 0;
        for (int bq = 0; bq < B_; ++bq) sum_ml += mellen[bq];
        out[0] = sm[0] / (float)sum_ml;
    }
}

extern "C" void kernel_launch(void* const* d_in, const int* in_sizes, int n_in,
                              void* d_out, int out_size, void* d_ws, size_t ws_size,
                              hipStream_t stream) {
    const float* m_p    = (const float*)d_in[0];
    const float* logs_p = (const float*)d_in[1];
    const float* z_p    = (const float*)d_in[2];
    const float* logs_q = (const float*)d_in[3];
    const int*   textlen = (const int*)d_in[4];
    const int*   mellen  = (const int*)d_in[5];

    float* out = (float*)d_out;
    float* attn = out + 1;                 // [B,T,S] region; also used as ll scratch
    float* ll = attn;

    char* ws = (char*)d_ws;
    const size_t OFF_BH   = 0;
    const size_t OFF_BL   = OFF_BH + (size_t)B_ * S_ * 384 * 2;  //  6291456
    const size_t OFF_NC   = OFF_BL + (size_t)B_ * S_ * 384 * 2;  // 12582912
    const size_t OFF_DIR  = OFF_NC + (size_t)B_ * S_ * 4;        // 12615680
    const size_t OFF_IDX  = OFF_DIR + (size_t)B_ * T_ * 64;      // 14712832
    const size_t OFF_FKL  = OFF_IDX + (size_t)B_ * T_ * 4;       // 14843904
    ushort_t* Bh = (ushort_t*)(ws + OFF_BH);
    ushort_t* Bl = (ushort_t*)(ws + OFF_BL);
    float* nc14 = (float*)(ws + OFF_NC);
    unsigned char* dir = (unsigned char*)(ws + OFF_DIR);
    int* idx_arr = (int*)(ws + OFF_IDX);
    float* frame_kl = (float*)(ws + OFF_FKL);

    // 1. prep (split B-side to bf16 hi/lo + nc14)
    prep_kernel<<<(B_ * S_) / 4, 256, 0, stream>>>(m_p, logs_p, Bh, Bl, nc14);
    // 2. score GEMM (split-bf16, 2-product) -> f32 ll
    gemm_kernel<<<dim3(S_ / 128, T_ / 128, B_), 256, 0, stream>>>(
        z_p, Bh, Bl, nc14, textlen, mellen, ll);
    // 3. MAS forward (R11-exact locked schedule)
    mas_forward<<<B_, 64, 0, stream>>>(ll, dir);
    // 4. MAS backward -> idx per frame
    mas_backward<<<B_, 64, 0, stream>>>(dir, textlen, mellen, idx_arr);
    // 5. fused attn write + per-frame kl
    attn_kl<<<(B_ * T_) / 4, 256, 0, stream>>>(m_p, logs_p, z_p, logs_q,
                                               idx_arr, mellen, attn, frame_kl);
    // 6. final reduce
    kl_reduce<<<1, 256, 0, stream>>>(frame_kl, mellen, out);
}

// Round 15
// 484.905 us; speedup vs baseline: 1.2696x; 1.0036x over previous
//
#include <hip/hip_runtime.h>

#define NEGV (-1e9f)

static const int B_ = 16;
static const int T_ = 2048;
static const int S_ = 512;
static const int C_ = 192;

typedef unsigned short ushort_t;
using f32x4 = __attribute__((ext_vector_type(4))) float;
using s16x8 = __attribute__((ext_vector_type(8))) short;

// split f32 into bf16 hi + bf16 lo (x ~= hi + lo, residual ~2^-18 |x|)
__device__ __forceinline__ void split2(float x, ushort_t& h, ushort_t& l) {
    __bf16 hb = (__bf16)x;
    h = __builtin_bit_cast(ushort_t, hb);
    float r = x - (float)hb;
    __bf16 lb = (__bf16)r;
    l = __builtin_bit_cast(ushort_t, lb);
}

__device__ __forceinline__ ushort_t to_bf16(float x) {
    return __builtin_bit_cast(ushort_t, (__bf16)x);
}

// ---------------- prep: Bcat = [m*s2r | s2r] split to bf16 hi/lo; nc14 ----------------
__global__ __launch_bounds__(256)
void prep_kernel(const float* __restrict__ m_p, const float* __restrict__ logs_p,
                 ushort_t* __restrict__ Bh, ushort_t* __restrict__ Bl,
                 float* __restrict__ nc14) {
    int wid = (blockIdx.x * blockDim.x + threadIdx.x) >> 6;   // (b*S+s)
    int lane = threadIdx.x & 63;
    if (wid >= B_ * S_) return;
    const float HALF_LOG_2PI = 0.9189385332046727f;
    const float* mrow = m_p    + (size_t)wid * C_;
    const float* lrow = logs_p + (size_t)wid * C_;
    ushort_t* bh = Bh + (size_t)wid * 384;
    ushort_t* bl = Bl + (size_t)wid * 384;
    float tot = 0.f;
#pragma unroll
    for (int q = 0; q < 3; ++q) {
        int c = lane + q * 64;
        float m  = mrow[c];
        float lp = lrow[c];
        float s2r = __expf(-2.f * lp);
        float a = m * s2r;
        ushort_t h, l;
        split2(a, h, l);   bh[c] = h;        bl[c] = l;
        split2(s2r, h, l); bh[192 + c] = h;  bl[192 + c] = l;
        tot += (-HALF_LOG_2PI - lp) + (-0.5f * m * m * s2r);
    }
#pragma unroll
    for (int off = 32; off > 0; off >>= 1) tot += __shfl_xor(tot, off);
    if (lane == 0) nc14[wid] = tot;
}

// ---------------- GEMM (split-bf16, 2 products): ll = masked(nc14 + A(z)*Bcat) ----------------
#define LDP 40   // LDS row stride in bf16 elems (32 + 8 pad)
__global__ __launch_bounds__(256)
void gemm_kernel(const float* __restrict__ z_p,
                 const ushort_t* __restrict__ Bh, const ushort_t* __restrict__ Bl,
                 const float* __restrict__ nc14,
                 const int* __restrict__ textlen, const int* __restrict__ mellen,
                 float* __restrict__ ll) {
    __shared__ ushort_t sAh[128 * LDP];
    __shared__ ushort_t sBh[128 * LDP];
    __shared__ ushort_t sBl[128 * LDP];

    const int b  = blockIdx.z;
    const int t0 = blockIdx.y * 128;
    const int s0 = blockIdx.x * 128;
    const int tid = threadIdx.x;
    const int lane = tid & 63;
    const int wave = tid >> 6;
    const int wr = wave >> 1, wc = wave & 1;
    const int srow = tid >> 1;
    const int cb = (tid & 1) * 16;

    const int ml = mellen[b], tl = textlen[b];
    const int r15 = lane & 15;
    const int klane = (lane >> 4) * 8;

    // ---- fully-masked tile: write NEGV and exit ----
    if (t0 >= ml || s0 >= tl) {
        int scol[4];
#pragma unroll
        for (int n = 0; n < 4; ++n) scol[n] = s0 + wc * 64 + n * 16 + r15;
#pragma unroll
        for (int m = 0; m < 4; ++m) {
            const int tb = t0 + wr * 64 + m * 16 + (lane >> 4) * 4;
#pragma unroll
            for (int r = 0; r < 4; ++r) {
                float* orow = ll + ((size_t)b * T_ + tb + r) * S_;
#pragma unroll
                for (int n = 0; n < 4; ++n) orow[scol[n]] = NEGV;
            }
        }
        return;
    }

    f32x4 acc[4][4];
#pragma unroll
    for (int m = 0; m < 4; ++m)
#pragma unroll
        for (int n = 0; n < 4; ++n) acc[m][n] = (f32x4){0.f, 0.f, 0.f, 0.f};

    for (int kk = 0; kk < 12; ++kk) {
        // ---- stage A from z_p (convert to bf16 hi only) ----
        {
            const int ck = (kk < 6 ? kk * 32 : (kk - 6) * 32) + cb;
            const float* src = z_p + ((size_t)b * T_ + t0 + srow) * C_ + ck;
            float e[16];
            *(float4*)(e + 0)  = *(const float4*)(src + 0);
            *(float4*)(e + 4)  = *(const float4*)(src + 4);
            *(float4*)(e + 8)  = *(const float4*)(src + 8);
            *(float4*)(e + 12) = *(const float4*)(src + 12);
            if (kk >= 6) {
#pragma unroll
                for (int i = 0; i < 16; ++i) e[i] = -0.5f * e[i] * e[i];
            }
            ushort_t h[16];
#pragma unroll
            for (int i = 0; i < 16; ++i) h[i] = to_bf16(e[i]);
            ushort_t* dh = &sAh[srow * LDP + cb];
            *(uint4*)dh = make_uint4(h[0] | (h[1] << 16), h[2] | (h[3] << 16),
                                     h[4] | (h[5] << 16), h[6] | (h[7] << 16));
            *(uint4*)(dh + 8) = make_uint4(h[8] | (h[9] << 16), h[10] | (h[11] << 16),
                                           h[12] | (h[13] << 16), h[14] | (h[15] << 16));
        }
        // ---- stage B from Bcat (already bf16 hi/lo) ----
        {
            const size_t off = ((size_t)b * S_ + s0 + srow) * 384 + kk * 32 + cb;
            const uint4 u0 = *(const uint4*)(Bh + off);
            const uint4 u1 = *(const uint4*)(Bh + off + 8);
            const uint4 v0 = *(const uint4*)(Bl + off);
            const uint4 v1 = *(const uint4*)(Bl + off + 8);
            ushort_t* dh = &sBh[srow * LDP + cb];
            ushort_t* dl = &sBl[srow * LDP + cb];
            *(uint4*)dh = u0; *(uint4*)(dh + 8) = u1;
            *(uint4*)dl = v0; *(uint4*)(dl + 8) = v1;
        }
        __syncthreads();

        s16x8 ah[4], bhf[4], blf[4];
#pragma unroll
        for (int m = 0; m < 4; ++m) {
            const int row = wr * 64 + m * 16 + r15;
            ah[m] = *(const s16x8*)&sAh[row * LDP + klane];
        }
#pragma unroll
        for (int n = 0; n < 4; ++n) {
            const int row = wc * 64 + n * 16 + r15;
            bhf[n] = *(const s16x8*)&sBh[row * LDP + klane];
            blf[n] = *(const s16x8*)&sBl[row * LDP + klane];
        }
#pragma unroll
        for (int m = 0; m < 4; ++m)
#pragma unroll
            for (int n = 0; n < 4; ++n) {
                acc[m][n] = __builtin_amdgcn_mfma_f32_16x16x32_bf16(ah[m], bhf[n], acc[m][n], 0, 0, 0);
                acc[m][n] = __builtin_amdgcn_mfma_f32_16x16x32_bf16(ah[m], blf[n], acc[m][n], 0, 0, 0);
            }
        __syncthreads();
    }

    // ---- epilogue: + nc14, mask, store f32 ----
    int scol[4]; float ncv[4];
#pragma unroll
    for (int n = 0; n < 4; ++n) {
        scol[n] = s0 + wc * 64 + n * 16 + r15;
        ncv[n] = nc14[b * S_ + scol[n]];
    }
#pragma unroll
    for (int m = 0; m < 4; ++m) {
        const int tb = t0 + wr * 64 + m * 16 + (lane >> 4) * 4;
#pragma unroll
        for (int r = 0; r < 4; ++r) {
            const int t = tb + r;
            const bool tm = (t < ml);
            float* orow = ll + ((size_t)b * T_ + t) * S_;
#pragma unroll
            for (int n = 0; n < 4; ++n)
                orow[scol[n]] = (tm && scol[n] < tl) ? (acc[m][n][r] + ncv[n]) : NEGV;
        }
    }
}

// ---------------- MAS forward: R11-EXACT locked schedule (do not touch) ----------------
__global__ __launch_bounds__(64)
void mas_forward(const float* __restrict__ ll, unsigned char* __restrict__ dir) {
    const int b = blockIdx.x;
    const int lane = threadIdx.x;
    const float* llb = ll + (size_t)b * T_ * S_ + lane * 8;
    unsigned char* db = dir + ((size_t)b * T_) * 64 + lane;
    const int sbase = lane * 8;

    float4 pre[8][2];
#pragma unroll
    for (int r = 0; r < 8; ++r) {
        pre[r][0] = *(const float4*)(llb + (size_t)r * S_);
        pre[r][1] = *(const float4*)(llb + (size_t)r * S_ + 4);
    }

    float p[8];
#pragma unroll
    for (int j = 0; j < 8; ++j) p[j] = 0.f;
    float carry = (lane == 0) ? NEGV : 0.f;

    auto step = [&](int t, int ph, bool masked) {
        float cur[8];
        cur[0] = pre[ph][0].x; cur[1] = pre[ph][0].y;
        cur[2] = pre[ph][0].z; cur[3] = pre[ph][0].w;
        cur[4] = pre[ph][1].x; cur[5] = pre[ph][1].y;
        cur[6] = pre[ph][1].z; cur[7] = pre[ph][1].w;
        const int tn = t + 8;
        if (tn < T_) {
            pre[ph][0] = *(const float4*)(llb + (size_t)tn * S_);
            pre[ph][1] = *(const float4*)(llb + (size_t)tn * S_ + 4);
        }
        float v7 = fmaxf(p[7], p[6]) + cur[7];
        float nc7 = masked ? ((sbase + 7 <= t) ? v7 : NEGV) : v7;
        float newcarry = __shfl_up(nc7, 1);

        unsigned bits = (p[0] >= carry) ? 1u : 0u;
#pragma unroll
        for (int j = 1; j < 8; ++j)
            bits |= (p[j] >= p[j - 1] ? 1u : 0u) << j;

        float nv[8];
        nv[0] = fmaxf(p[0], carry) + cur[0];
#pragma unroll
        for (int j = 1; j < 7; ++j) nv[j] = fmaxf(p[j], p[j - 1]) + cur[j];
        nv[7] = v7;
        if (masked) {
#pragma unroll
            for (int j = 0; j < 8; ++j)
                p[j] = (sbase + j <= t) ? nv[j] : NEGV;
        } else {
#pragma unroll
            for (int j = 0; j < 8; ++j) p[j] = nv[j];
        }
        carry = (lane == 0) ? NEGV : newcarry;
        db[(size_t)t * 64] = (unsigned char)bits;
    };

    for (int to = 0; to < S_ / 8; ++to) {
#pragma unroll
        for (int ph = 0; ph < 8; ++ph) step(to * 8 + ph, ph, true);
    }
    for (int to = S_ / 8; to < T_ / 8; ++to) {
#pragma unroll
        for (int ph = 0; ph < 8; ++ph) step(to * 8 + ph, ph, false);
    }
}

// ---------------- MAS backward: 2-deep speculative window prefetch ----------------
// idx drops <=8 per group, so a 4-byte window [B-3, B] (B = anchor>>3) anchored
// at the idx from TWO groups earlier provably covers all byte reads of the
// current group (reads at idx in [anchor-23, anchor] -> bytes [B-3, B]).
// Prefetching 2 groups ahead hides load latency under two resolve periods.
__global__ __launch_bounds__(64)
void mas_backward(const unsigned char* __restrict__ dir,
                  const int* __restrict__ textlen, const int* __restrict__ mellen,
                  int* __restrict__ idx_arr) {
    const int b = blockIdx.x;
    const int lane = threadIdx.x;
    const int tl = textlen[b], ml = mellen[b];
    for (int t = ml + lane; t < T_; t += 64) idx_arr[b * T_ + t] = -1;
    const unsigned char* db = dir + (size_t)b * T_ * 64;
    int idx = tl - 1;
    int t_hi = ml - 1;

    auto loadwin = [&](int throw_, int anchor, int& base) -> unsigned {
        const int B = anchor >> 3;
        const int b0 = (B > 3) ? (B - 3) : 0;
        base = b0;
        unsigned w = 0;
        const int t = throw_ - lane;          // lanes 0..7 cover the 8 rows
        if (lane < 8 && t >= 0) {
            const unsigned char* p = db + (size_t)t * 64 + b0;
            w = (unsigned)p[0] | ((unsigned)p[1] << 8) |
                ((unsigned)p[2] << 16) | ((unsigned)p[3] << 24);
        }
        return w;
    };

    int b00, b01;
    unsigned w0 = loadwin(t_hi, idx, b00);        // group 0 (anchor exact)
    unsigned w1 = loadwin(t_hi - 8, idx, b01);    // group 1 (anchor covers -16)

    while (t_hi >= 0) {
        int b02;
        unsigned w2 = loadwin(t_hi - 16, idx, b02);   // prefetch group g+2

        unsigned vk[8];
#pragma unroll
        for (int k = 0; k < 8; ++k) vk[k] = __shfl((int)w0, k);
        int emit = -1;
#pragma unroll
        for (int k = 0; k < 8; ++k) {
            const int tt = t_hi - k;
            if (tt < 0) break;
            if (lane == k) emit = idx;
            const int off = (idx >> 3) - b00;          // in [0,3] by coverage proof
            const unsigned byte = (vk[k] >> (off * 8)) & 0xffu;
            const int stay = (byte >> (idx & 7)) & 1;
            idx -= (1 - stay);
            if (idx < 0) idx = 0;
        }
        const int tt = t_hi - lane;
        if (lane < 8 && tt >= 0) idx_arr[b * T_ + tt] = emit;
        w0 = w1; b00 = b01;
        w1 = w2; b01 = b02;
        t_hi -= 8;
    }
}

// ---------------- fused attn write + per-frame kl ----------------
__global__ __launch_bounds__(256)
void attn_kl(const float* __restrict__ m_p, const float* __restrict__ logs_p,
             const float* __restrict__ z_p, const float* __restrict__ logs_q,
             const int* __restrict__ idx_arr, const int* __restrict__ mellen,
             float* __restrict__ attn, float* __restrict__ frame_kl) {
    const int wid = (blockIdx.x * blockDim.x + threadIdx.x) >> 6;  // b*T + t
    const int lane = threadIdx.x & 63;
    if (wid >= B_ * T_) return;
    const int b = wid >> 11;       // T_ = 2048
    const int t = wid & (T_ - 1);
    const int ml = mellen[b];
    const int idx = idx_arr[wid];  // -1 for t >= ml

    float* row = attn + (size_t)wid * S_;
#pragma unroll
    for (int j = 0; j < 8; ++j) {
        const int s = j * 64 + lane;
        row[s] = (s == idx) ? 1.0f : 0.0f;
    }

    float total = 0.f;
    if (t < ml) {
        const float* mr = m_p    + ((size_t)b * S_ + idx) * C_;
        const float* lr = logs_p + ((size_t)b * S_ + idx) * C_;
        const float* zr = z_p    + (size_t)wid * C_;
        const float* qr = logs_q + (size_t)wid * C_;
#pragma unroll
        for (int q = 0; q < 3; ++q) {
            const int c = lane + q * 64;
            const float le = lr[c];
            const float d = zr[c] - mr[c];
            total += le - qr[c] - 0.5f + 0.5f * d * d * __expf(-2.f * le);
        }
    }
#pragma unroll
    for (int off = 32; off > 0; off >>= 1) total += __shfl_xor(total, off);
    if (lane == 0) frame_kl[wid] = total;
}

// ---------------- deterministic final reduce ----------------
__global__ __launch_bounds__(256)
void kl_reduce(const float* __restrict__ frame_kl, const int* __restrict__ mellen,
               float* __restrict__ out) {
    __shared__ float sm[256];
    const int tid = threadIdx.x;
    float s = 0.f;
    for (int k = tid; k < B_ * T_; k += 256) s += frame_kl[k];
    sm[tid] = s;
    __syncthreads();
    for (int off = 128; off > 0; off >>= 1) {
        if (tid < off) sm[tid] += sm[tid + off];
        __syncthreads();
    }
    if (tid == 0) {
        int sum_ml = 0;
        for (int bq = 0; bq < B_; ++bq) sum_ml += mellen[bq];
        out[0] = sm[0] / (float)sum_ml;
    }
}

extern "C" void kernel_launch(void* const* d_in, const int* in_sizes, int n_in,
                              void* d_out, int out_size, void* d_ws, size_t ws_size,
                              hipStream_t stream) {
    const float* m_p    = (const float*)d_in[0];
    const float* logs_p = (const float*)d_in[1];
    const float* z_p    = (const float*)d_in[2];
    const float* logs_q = (const float*)d_in[3];
    const int*   textlen = (const int*)d_in[4];
    const int*   mellen  = (const int*)d_in[5];

    float* out = (float*)d_out;
    float* attn = out + 1;                 // [B,T,S] region; also used as ll scratch
    float* ll = attn;

    char* ws = (char*)d_ws;
    const size_t OFF_BH   = 0;
    const size_t OFF_BL   = OFF_BH + (size_t)B_ * S_ * 384 * 2;  //  6291456
    const size_t OFF_NC   = OFF_BL + (size_t)B_ * S_ * 384 * 2;  // 12582912
    const size_t OFF_DIR  = OFF_NC + (size_t)B_ * S_ * 4;        // 12615680
    const size_t OFF_IDX  = OFF_DIR + (size_t)B_ * T_ * 64;      // 14712832
    const size_t OFF_FKL  = OFF_IDX + (size_t)B_ * T_ * 4;       // 14843904
    ushort_t* Bh = (ushort_t*)(ws + OFF_BH);
    ushort_t* Bl = (ushort_t*)(ws + OFF_BL);
    float* nc14 = (float*)(ws + OFF_NC);
    unsigned char* dir = (unsigned char*)(ws + OFF_DIR);
    int* idx_arr = (int*)(ws + OFF_IDX);
    float* frame_kl = (float*)(ws + OFF_FKL);

    // 1. prep (split B-side to bf16 hi/lo + nc14)
    prep_kernel<<<(B_ * S_) / 4, 256, 0, stream>>>(m_p, logs_p, Bh, Bl, nc14);
    // 2. score GEMM (split-bf16, 2-product) -> f32 ll
    gemm_kernel<<<dim3(S_ / 128, T_ / 128, B_), 256, 0, stream>>>(
        z_p, Bh, Bl, nc14, textlen, mellen, ll);
    // 3. MAS forward (R11-exact locked schedule)
    mas_forward<<<B_, 64, 0, stream>>>(ll, dir);
    // 4. MAS backward (2-deep speculative prefetch) -> idx per frame
    mas_backward<<<B_, 64, 0, stream>>>(dir, textlen, mellen, idx_arr);
    // 5. fused attn write + per-frame kl
    attn_kl<<<(B_ * T_) / 4, 256, 0, stream>>>(m_p, logs_p, z_p, logs_q,
                                               idx_arr, mellen, attn, frame_kl);
    // 6. final reduce
    kl_reduce<<<1, 256, 0, stream>>>(frame_kl, mellen, out);
}